// Round 13
// baseline (292.362 us; speedup 1.0000x reference)
//
#include <hip/hip_runtime.h>

#define NB 8
#define NH 512
#define NW 640
#define NHW (NH*NW)
#define NBHW (NB*NHW)
#define TOPK 512
#define CAP 40960
#define PAD 8
#define CNT_STRIDE 64   // totals: one counter per 256B cacheline
#define NBIN 1024       // fine value-buckets per list (linear in d = 1.0f-bits distance)
#define GCAP 4096       // topk gather capacity (32 KB LDS)

// NMS tile geometry (block = 256 threads)
#define TW 64
#define TH 32
#define INH 36          // staged rows:  gy in [by*32-2, by*32+34)
#define INW 72          // staged cols (src0 covers -4..67, src1 covers -2..69)

// Gaussian taps exp(-2 d^2); |d|>=3 taps are <=1.52e-8 -> negligible, radius 2 used
#define G0 1.0f
#define G1 0.1353352832366127f
#define G2 3.3546262790251185e-4f

__device__ __forceinline__ float bordered(const float* __restrict__ img, int b, int y, int x) {
  if (y < PAD || y >= NH - PAD || x < PAD || x >= NW - PAD) return 0.f;
  return img[b * NHW + y * NW + x];
}

// Fine bucket, monotone NON-DECREASING in d (i.e. decreasing in val).
// Resolution 2^-14 in val near 1.0 where 5x5-max survivors crowd.
__device__ __forceinline__ int dbucket(float val) {
  int d = 0x3F800000 - (int)__float_as_uint(val);
  if (d < 0) d = 0;
  int bk = d >> 10;
  return bk > (NBIN - 1) ? (NBIN - 1) : bk;
}

__device__ __forceinline__ void corner(const float* __restrict__ img, float cx, float cy,
                                       float wgt, float& acc) {
  float valid = (cx >= 0.f && cx <= (float)(NW - 1) && cy >= 0.f && cy <= (float)(NH - 1)) ? 1.f : 0.f;
  float xc = fminf(fmaxf(cx, 0.f), (float)(NW - 1));
  float yc = fminf(fmaxf(cy, 0.f), (float)(NH - 1));
  int xi = (int)xc, yi = (int)yc;
  acc += wgt * img[yi * NW + xi] * valid;
}

// Division-free visibility: v=1 iff x2 in (-1,NW) and y2 in (-1,NH), x2=X/Z.
__device__ __forceinline__ float vis_quad(float h0, float h1, float h2, float h3, float h4,
                                          float h5, float h6, float h7, float h8,
                                          float xf, float yf) {
  float X = h0 * xf + h1 * yf + h2;
  float Y = h3 * xf + h4 * yf + h5;
  float Z = h6 * xf + h7 * yf + h8;
  bool ok = ((X + Z) * Z > 0.f) & ((640.f * Z - X) * Z > 0.f)
          & ((Y + Z) * Z > 0.f) & ((512.f * Z - Y) * Z > 0.f);
  return ok ? 1.f : 0.f;
}

// The five linear factors whose signs determine vis. Linear in (x,y) -> sign
// uniform on a rect iff uniform at its 4 corners.
__device__ __forceinline__ void vis_parts(float h0, float h1, float h2, float h3, float h4,
                                          float h5, float h6, float h7, float h8,
                                          float xf, float yf, float L[5]) {
  float X = h0 * xf + h1 * yf + h2;
  float Y = h3 * xf + h4 * yf + h5;
  float Z = h6 * xf + h7 * yf + h8;
  L[0] = X + Z; L[1] = 640.f * Z - X; L[2] = Y + Z; L[3] = 512.f * Z - Y; L[4] = Z;
}

// Fused warp + border-filter + 5x5 separable NMS + fine-bucket counts (+dense loss, src0).
__global__ __launch_bounds__(256) void k_nms4(
    const float* __restrict__ score1, const float* __restrict__ score2,
    const float* __restrict__ homo,
    unsigned long long* __restrict__ lists, unsigned int* __restrict__ cbase,
    unsigned int* __restrict__ bins, unsigned long long* __restrict__ accum) {
  int bx = blockIdx.x, by = blockIdx.y;
  int src = blockIdx.z >> 3, b = blockIdx.z & 7;
  int tid = threadIdx.x;

  __shared__ float in[INH][INW];       // 10.1 KB
  __shared__ float hmax[INH][TW];      // 9.0 KB
  __shared__ unsigned int s_cnt, s_base;
  __shared__ float s_wsum[4];
  __shared__ unsigned int s_wcnt[4];

  if (tid == 0) { s_cnt = 0; s_base = 0; }

  const float* hm = homo + b * 9;
  float h0 = hm[0], h1 = hm[1], h2 = hm[2];
  float h3 = hm[3], h4 = hm[4], h5 = hm[5];
  float h6 = hm[6], h7 = hm[7], h8 = hm[8];

  int y0t = by * TH, x0t = bx * TW;
  int li = src * NB + b;

  // Phase 1: stage tile into LDS (compile-time trip counts -> unrolled, deep MLP)
  if (src == 0) {
    #pragma unroll
    for (int it = 0; it < 3; ++it) {
      int i = it * 256 + tid;
      if (i < INH * 18) {
        int r = i / 18, c4 = i % 18;
        int gy = y0t + r - 2;
        int gx0 = x0t - 4 + c4 * 4;
        float4 v = make_float4(0.f, 0.f, 0.f, 0.f);
        if (gy >= PAD && gy < NH - PAD) {
          const float4* p = (const float4*)(score1 + (size_t)b * NHW + (size_t)gy * NW + gx0);
          float4 raw = *p;
          v.x = (gx0 + 0 >= PAD && gx0 + 0 < NW - PAD) ? raw.x : 0.f;
          v.y = (gx0 + 1 >= PAD && gx0 + 1 < NW - PAD) ? raw.y : 0.f;
          v.z = (gx0 + 2 >= PAD && gx0 + 2 < NW - PAD) ? raw.z : 0.f;
          v.w = (gx0 + 3 >= PAD && gx0 + 3 < NW - PAD) ? raw.w : 0.f;
        }
        *(float4*)&in[r][c4 * 4] = v;
      }
    }
  } else {
    const float* img = score2 + b * NHW;
    #pragma unroll
    for (int it = 0; it < 10; ++it) {
      int i = it * 256 + tid;
      if (i < INH * 68) {
        int r = i / 68, c = i % 68;
        int gy = y0t + r - 2, gx = x0t - 2 + c;
        float v = 0.f;
        if (gy >= PAD && gy < NH - PAD && gx >= PAD && gx < NW - PAD) {
          float xf = (float)gx, yf = (float)gy;
          float X = h0 * xf + h1 * yf + h2;
          float Y = h3 * xf + h4 * yf + h5;
          float Z = h6 * xf + h7 * yf + h8;
          float rz = __builtin_amdgcn_rcpf(Z);
          float x2 = X * rz, y2 = Y * rz;
          float x0f = floorf(x2), y0f = floorf(y2);
          float x1f = x0f + 1.f, y1f = y0f + 1.f;
          float wa = (x1f - x2) * (y1f - y2);
          float wb = (x2 - x0f) * (y1f - y2);
          float wc = (x1f - x2) * (y2 - y0f);
          float wd = (x2 - x0f) * (y2 - y0f);
          float acc = 0.f;
          if (x0f >= 0.f && x1f <= 639.f && y0f >= 0.f && y1f <= 511.f) {
            const float* p = img + (int)y0f * NW + (int)x0f;
            acc = fmaf(wa, p[0], acc);
            acc = fmaf(wb, p[1], acc);
            acc = fmaf(wc, p[NW], acc);
            acc = fmaf(wd, p[NW + 1], acc);
          } else {
            corner(img, x0f, y0f, wa, acc);
            corner(img, x1f, y0f, wb, acc);
            corner(img, x0f, y1f, wc, acc);
            corner(img, x1f, y1f, wd, acc);
          }
          v = acc;
        }
        in[r][c + 2] = v;
      }
    }
  }
  __syncthreads();

  // Phase 2: horizontal 5-max. hmax[r][c] = max(in[r][c+2 .. c+6])
  #pragma unroll
  for (int it = 0; it < 9; ++it) {
    int i = it * 256 + tid;
    int r = i >> 6, c = i & 63;
    float m = fmaxf(fmaxf(fmaxf(in[r][c + 2], in[r][c + 3]), fmaxf(in[r][c + 4], in[r][c + 5])),
                    in[r][c + 6]);
    hmax[r][c] = m;
  }
  __syncthreads();

  // src0: block-uniform visibility shortcut (5 linear factors, 4 tile corners)
  bool uni = false;
  float vconst = 0.f;
  if (src == 0) {
    float c00[5], c10[5], c01[5], c11[5];
    vis_parts(h0, h1, h2, h3, h4, h5, h6, h7, h8, (float)x0t, (float)y0t, c00);
    vis_parts(h0, h1, h2, h3, h4, h5, h6, h7, h8, (float)(x0t + TW - 1), (float)y0t, c10);
    vis_parts(h0, h1, h2, h3, h4, h5, h6, h7, h8, (float)x0t, (float)(y0t + TH - 1), c01);
    vis_parts(h0, h1, h2, h3, h4, h5, h6, h7, h8, (float)(x0t + TW - 1), (float)(y0t + TH - 1), c11);
    uni = true;
    bool sig[5];
    #pragma unroll
    for (int q = 0; q < 5; ++q) {
      bool allp = (c00[q] > 0.f) & (c10[q] > 0.f) & (c01[q] > 0.f) & (c11[q] > 0.f);
      bool alln = (c00[q] < 0.f) & (c10[q] < 0.f) & (c01[q] < 0.f) & (c11[q] < 0.f);
      uni = uni & (allp | alln);
      sig[q] = allp;
    }
    vconst = (sig[0] == sig[4] && sig[1] == sig[4] && sig[2] == sig[4] && sig[3] == sig[4])
             ? 1.f : 0.f;
  }

  // Phase 3: vertical 5-max + survivor detection; src0 also dense loss terms
  int nsv = 0;
  float sv[8];
  unsigned int si[8];
  float tsum = 0.f;
  int vcnt = 0;
  #pragma unroll
  for (int it = 0; it < (TH * TW) / 256; ++it) {
    int i = it * 256 + tid;
    int r = i >> 6, c = i & 63;
    int gy = y0t + r, gx = x0t + c;
    float val = in[r + 2][c + 4];
    if (src == 0) {
      float v = uni ? vconst
                    : vis_quad(h0, h1, h2, h3, h4, h5, h6, h7, h8, (float)gx, (float)gy);
      tsum += val * val * v;
      vcnt += (v > 0.f) ? 1 : 0;
    }
    if (val > 0.f) {   // NMS_THRESH = 0
      float m = fmaxf(fmaxf(fmaxf(hmax[r][c], hmax[r + 1][c]), fmaxf(hmax[r + 2][c], hmax[r + 3][c])),
                      hmax[r + 4][c]);
      if (m == val) {
        sv[nsv] = val;
        si[nsv] = (unsigned int)(gy * NW + gx);
        ++nsv;
      }
    }
  }

  // Phase 4: list slot reservation + fine-bucket global atomics (scattered, uncontended)
  unsigned int local = 0;
  if (nsv > 0) local = atomicAdd(&s_cnt, (unsigned int)nsv);
  #pragma unroll
  for (int j = 0; j < 8; ++j)
    if (j < nsv) atomicAdd(&bins[li * NBIN + dbucket(sv[j])], 1u);

  if (src == 0) {
    for (int m = 1; m < 64; m <<= 1) {
      tsum += __shfl_xor(tsum, m, 64);
      vcnt += __shfl_xor(vcnt, m, 64);
    }
    if ((tid & 63) == 0) { s_wsum[tid >> 6] = tsum; s_wcnt[tid >> 6] = (unsigned int)vcnt; }
  }
  __syncthreads();

  if (tid == 0) {
    if (s_cnt > 0) s_base = atomicAdd(&cbase[li * CNT_STRIDE], s_cnt);
    if (src == 0) {
      float ts = s_wsum[0] + s_wsum[1] + s_wsum[2] + s_wsum[3];
      unsigned int vc = s_wcnt[0] + s_wcnt[1] + s_wcnt[2] + s_wcnt[3];
      long long fp = (long long)((double)ts * 4294967296.0);
      atomicAdd(&accum[0], (unsigned long long)fp);
      atomicAdd(&accum[1], (unsigned long long)vc);
    }
  }
  __syncthreads();

  unsigned int base = s_base;
  #pragma unroll
  for (int j = 0; j < 8; ++j) {
    if (j < nsv) {
      unsigned int pos = base + local + (unsigned int)j;
      if (pos < CAP) {
        unsigned long long key = ((unsigned long long)__float_as_uint(sv[j]) << 32)
                               | (unsigned long long)(~si[j]);
        lists[(size_t)li * CAP + pos] = key;
      }
    }
  }
}

// Exact top-512 per (source,image): 1024 fine bins -> parallel scan -> boundary bin
// -> one gather scan (total ~ 520) -> rank select by full 64-bit key.
// src0 -> kp1 out. src1 -> winners rank-sorted by pixel idx asc, written compact.
#define NT 1024
__global__ __launch_bounds__(NT) void k_topk7(
    const unsigned long long* __restrict__ lists, const unsigned int* __restrict__ cbase,
    const unsigned int* __restrict__ bins,
    float* __restrict__ out, unsigned long long* __restrict__ winners,
    unsigned int* __restrict__ wcnt) {
  int li = blockIdx.x;             // 0..15
  int src = li >> 3, b = li & 7;
  int tid = threadIdx.x;

  __shared__ unsigned long long sbuf[GCAP];   // 32 KB candidates
  __shared__ unsigned long long srt[TOPK];    // top-512 sorted desc by (val, idx-asc)
  __shared__ unsigned int s_sc[NBIN];         // 4 KB bin counts / inclusive scan
  __shared__ int s_bb;
  __shared__ unsigned int s_nsel;

  unsigned int N = cbase[li * CNT_STRIDE]; if (N > CAP) N = CAP;
  s_sc[tid] = bins[li * NBIN + tid];
  if (tid == 0) { s_nsel = 0; s_bb = -1; }
  __syncthreads();

  // inclusive prefix scan over 1024 bins (bin 0 = highest values)
  for (int off = 1; off < NBIN; off <<= 1) {
    unsigned int v = (tid >= off) ? s_sc[tid - off] : 0u;
    __syncthreads();
    s_sc[tid] += v;
    __syncthreads();
  }
  unsigned int want = (N < TOPK) ? N : TOPK;
  unsigned int cum = s_sc[tid];
  unsigned int prev = (tid == 0) ? 0u : s_sc[tid - 1];
  if (want > 0 && cum >= want && prev < want) s_bb = tid;
  __syncthreads();
  int bb = s_bb;

  // single gather scan with wave-aggregated LDS push (total = cum(bb) ~ want + eps)
  const unsigned long long* list = lists + (size_t)li * CAP;
  int lane = tid & 63;
  for (unsigned int i = tid; i < N; i += NT) {
    unsigned long long k = list[i];
    float v = __uint_as_float((unsigned int)(k >> 32));
    bool pred = (dbucket(v) <= bb);
    unsigned long long mask = __ballot(pred);
    if (mask) {
      int leader = __ffsll((long long)mask) - 1;
      unsigned int cnt = (unsigned int)__popcll(mask);
      unsigned int bp = 0;
      if (lane == leader) bp = atomicAdd(&s_nsel, cnt);
      bp = __shfl(bp, leader, 64);
      if (pred) {
        unsigned int pos = bp + (unsigned int)__popcll(mask & ((1ULL << lane) - 1ULL));
        if (pos < GCAP) sbuf[pos] = k;
      }
    }
  }
  __syncthreads();
  unsigned int total = s_nsel; if (total > GCAP) total = GCAP;

  // rank selection: top-512 by full 64-bit key (val desc, idx asc), exact.
  // LDS reads are wave-broadcast (all lanes read the same address).
  for (unsigned int i = tid; i < total; i += NT) {
    unsigned long long key = sbuf[i];
    unsigned int rank = 0;
    for (unsigned int j = 0; j < total; ++j)
      rank += (sbuf[j] > key) ? 1u : 0u;
    if (rank < TOPK) srt[rank] = key;
  }
  for (unsigned int i = total + tid; i < TOPK; i += NT) srt[i] = 0ULL;
  __syncthreads();

  if (src == 0) {
    for (int r = tid; r < TOPK; r += NT) {
      unsigned long long k = srt[r];
      unsigned int idx = (k == 0ULL) ? 0u : ~(unsigned int)(k & 0xFFFFFFFFULL);
      int yy = (int)(idx / NW), xx = (int)(idx % NW);
      out[1 + ((b * TOPK) + r) * 2 + 0] = (float)yy;
      out[1 + ((b * TOPK) + r) * 2 + 1] = (float)xx;
    }
  } else {
    unsigned int nw = (total < TOPK) ? total : TOPK;
    // rank by pixel idx asc among winners; write (idx<<32)|valbits compact
    for (unsigned int i = tid; i < nw; i += NT) {
      unsigned long long k = srt[i];
      unsigned int idx = ~(unsigned int)(k & 0xFFFFFFFFULL);
      unsigned int rank = 0;
      for (unsigned int j = 0; j < nw; ++j) {
        unsigned int idxj = ~(unsigned int)(srt[j] & 0xFFFFFFFFULL);
        rank += (idxj < idx) ? 1u : 0u;
      }
      winners[b * TOPK + rank] = ((unsigned long long)idx << 32) | (k >> 32);
    }
    for (unsigned int i = nw + tid; i < TOPK; i += NT) winners[b * TOPK + i] = ~0ULL;
    if (tid == 0) wcnt[b] = nw;
  }
}

// Sparse gt + correction, gather-based (no gtbuf):
// task = (winner i, tap k). Pixel p = pos_i + offset(k). Contributors found by
// binary search over winners sorted by idx; min-idx contributor owns p.
// Fully deterministic (fixed scan order; integer accumulation only).
__global__ __launch_bounds__(256) void k_gt(
    const float* __restrict__ score1, const float* __restrict__ homo,
    const unsigned long long* __restrict__ winners, const unsigned int* __restrict__ wcnt,
    unsigned long long* __restrict__ accum, unsigned int* __restrict__ dcnt,
    float* __restrict__ out) {
  int b = blockIdx.y;
  int tid = threadIdx.x;
  __shared__ unsigned long long w[TOPK];
  __shared__ float s_red[4];

  unsigned int nw = wcnt[b];
  for (int i = tid; i < TOPK; i += 256)
    w[i] = (i < (int)nw) ? winners[b * TOPK + i] : ~0ULL;
  __syncthreads();

  const float* hm = homo + b * 9;
  float h0 = hm[0], h1 = hm[1], h2 = hm[2];
  float h3 = hm[3], h4 = hm[4], h5 = hm[5];
  float h6 = hm[6], h7 = hm[7], h8 = hm[8];

  const float gw5[5] = {G2, G1, G0, G1, G2};
  unsigned int r = blockIdx.x * 256u + (unsigned int)tid;  // task id in image
  unsigned int i = r / 25u, k = r % 25u;
  float term = 0.f;
  if (i < nw) {
    unsigned long long wk = w[i];
    unsigned int idx = (unsigned int)(wk >> 32);
    int y = (int)(idx / NW), x = (int)(idx % NW);
    int py = y + (int)(k / 5u) - 2, px = x + (int)(k % 5u) - 2;

    float gt = 0.f;
    unsigned int firstIdx = 0xFFFFFFFFu;
    #pragma unroll
    for (int dr = -2; dr <= 2; ++dr) {
      int ry = py + dr;
      unsigned int lo = (unsigned int)(ry * NW + px - 2);
      unsigned int hi = (unsigned int)(ry * NW + px + 2);
      unsigned long long lokey = ((unsigned long long)lo << 32);
      int a = 0, e = TOPK;
      while (a < e) { int m = (a + e) >> 1; if (w[m] < lokey) a = m + 1; else e = m; }
      for (int j = a; j < TOPK; ++j) {
        unsigned long long c = w[j];
        unsigned int cidx = (unsigned int)(c >> 32);
        if (cidx > hi) break;
        float cval = __uint_as_float((unsigned int)(c & 0xFFFFFFFFULL));
        int cx = (int)(cidx % NW);
        gt += cval * gw5[dr + 2] * gw5[cx - px + 2];
        if (firstIdx == 0xFFFFFFFFu) firstIdx = cidx;
      }
    }
    if (firstIdx == idx) {   // this winner owns pixel p -> exactly-once
      float s1 = bordered(score1, b, py, px);
      float v = vis_quad(h0, h1, h2, h3, h4, h5, h6, h7, h8, (float)px, (float)py);
      term = (gt - 2.f * s1) * gt * v;
    }
  }

  for (int m = 1; m < 64; m <<= 1) term += __shfl_xor(term, m, 64);
  if ((tid & 63) == 0) s_red[tid >> 6] = term;
  __syncthreads();
  if (tid == 0) {
    float bsum = s_red[0] + s_red[1] + s_red[2] + s_red[3];
    long long fp = (long long)((double)bsum * 4294967296.0);
    atomicAdd(&accum[0], (unsigned long long)fp);
    __threadfence();
    unsigned int old = atomicAdd(dcnt, 1u);
    if (old == gridDim.x * gridDim.y - 1u) {
      unsigned long long ts = atomicAdd(&accum[0], 0ULL);
      unsigned long long nv = atomicAdd(&accum[1], 0ULL);
      double tsd = (double)(long long)ts / 4294967296.0;
      out[0] = (float)(100.0 * tsd / (double)nv);
    }
  }
}

extern "C" void kernel_launch(void* const* d_in, const int* in_sizes, int n_in,
                              void* d_out, int out_size, void* d_ws, size_t ws_size,
                              hipStream_t stream) {
  const float* score1 = (const float*)d_in[0];
  const float* score2 = (const float*)d_in[1];
  const float* homo   = (const float*)d_in[2];
  float* out = (float*)d_out;

  // workspace layout
  unsigned long long* lists = (unsigned long long*)d_ws;            // 16*CAP u64
  unsigned int* cbase = (unsigned int*)(lists + (size_t)16 * CAP);
  // cbase u32 indices: [0,1024) padded totals; [1024, 1024+16*NBIN) fine bins;
  // then accum (2 u64), dcnt, wcnt[8], winners (8-byte aligned)
  unsigned int* bins = cbase + 1024;
  unsigned long long* accum = (unsigned long long*)(cbase + 1024 + 16 * NBIN); // idx 17408
  unsigned int* dcnt = cbase + 17412;
  unsigned int* wcnt = cbase + 17416;                                // 8 u32
  unsigned long long* winners = (unsigned long long*)(cbase + 17424); // 8*512 u64
  const size_t cbytes = 17416 * 4;   // memset: totals + bins + accum + dcnt

  size_t required = (size_t)16 * CAP * 8 + 17424 * 4 + (size_t)NB * TOPK * 8;
  if (ws_size < required) return;

  hipMemsetAsync(cbase, 0, cbytes, stream);

  dim3 gnms(NW / TW, NH / TH, 16);    // 10 x 16 x 16 = 2560 blocks
  k_nms4<<<gnms, 256, 0, stream>>>(score1, score2, homo, lists, cbase, bins, accum);
  k_topk7<<<16, NT, 0, stream>>>(lists, cbase, bins, out, winners, wcnt);
  dim3 ggt((TOPK * 25) / 256, NB);    // 50 x 8 = 400 blocks
  k_gt<<<ggt, 256, 0, stream>>>(score1, homo, winners, wcnt, accum, dcnt, out);
}

// Round 14
// 109.411 us; speedup vs baseline: 2.6721x; 2.6721x over previous
//
#include <hip/hip_runtime.h>

#define NB 8
#define NH 512
#define NW 640
#define NHW (NH*NW)
#define NBHW (NB*NHW)
#define TOPK 512
#define CAP 40960
#define PAD 8
#define CNT_STRIDE 64    // totals: one counter per 256B cacheline
#define BUCKET_BASE 1024 // u32 index of bucket counters in cbase (unpadded)
#define NBUCKET 32
#define GCAP 4096        // topk gather capacity (32 KB LDS)

// NMS tile geometry (block = 256 threads)
#define TW 64
#define TH 32
#define INH 36          // staged rows:  gy in [by*32-2, by*32+34)
#define INW 72          // staged cols (src0 covers -4..67, src1 covers -2..69)

// Gaussian taps exp(-2 d^2); |d|>=3 taps are <=1.52e-8 -> negligible, radius 2 used
#define G0 1.0f
#define G1 0.1353352832366127f
#define G2 3.3546262790251185e-4f

__device__ __forceinline__ float bordered(const float* __restrict__ img, int b, int y, int x) {
  if (y < PAD || y >= NH - PAD || x < PAD || x >= NW - PAD) return 0.f;
  return img[b * NHW + y * NW + x];
}

// Monotone (weakly increasing in val) bucket index, fine-grained near 1.0.
__device__ __forceinline__ int vbucket(float val) {
  int d = 0x3F800000 - (int)__float_as_uint(val);
  if (d <= 0) return NBUCKET - 1;
  int c = __clz(d);
  return c > 30 ? 30 : c;
}

__device__ __forceinline__ void corner(const float* __restrict__ img, float cx, float cy,
                                       float wgt, float& acc) {
  float valid = (cx >= 0.f && cx <= (float)(NW - 1) && cy >= 0.f && cy <= (float)(NH - 1)) ? 1.f : 0.f;
  float xc = fminf(fmaxf(cx, 0.f), (float)(NW - 1));
  float yc = fminf(fmaxf(cy, 0.f), (float)(NH - 1));
  int xi = (int)xc, yi = (int)yc;
  acc += wgt * img[yi * NW + xi] * valid;
}

// Division-free visibility: v=1 iff x2 in (-1,NW) and y2 in (-1,NH), x2=X/Z.
__device__ __forceinline__ float vis_quad(float h0, float h1, float h2, float h3, float h4,
                                          float h5, float h6, float h7, float h8,
                                          float xf, float yf) {
  float X = h0 * xf + h1 * yf + h2;
  float Y = h3 * xf + h4 * yf + h5;
  float Z = h6 * xf + h7 * yf + h8;
  bool ok = ((X + Z) * Z > 0.f) & ((640.f * Z - X) * Z > 0.f)
          & ((Y + Z) * Z > 0.f) & ((512.f * Z - Y) * Z > 0.f);
  return ok ? 1.f : 0.f;
}

// The five linear factors whose signs determine vis. Linear in (x,y) -> sign
// uniform on a rect iff uniform at its 4 corners.
__device__ __forceinline__ void vis_parts(float h0, float h1, float h2, float h3, float h4,
                                          float h5, float h6, float h7, float h8,
                                          float xf, float yf, float L[5]) {
  float X = h0 * xf + h1 * yf + h2;
  float Y = h3 * xf + h4 * yf + h5;
  float Z = h6 * xf + h7 * yf + h8;
  L[0] = X + Z; L[1] = 640.f * Z - X; L[2] = Y + Z; L[3] = 512.f * Z - Y; L[4] = Z;
}

// Fused warp + border-filter + 5x5 separable NMS + LDS bucket hist (+dense loss, src0).
__global__ __launch_bounds__(256) void k_nms4(
    const float* __restrict__ score1, const float* __restrict__ score2,
    const float* __restrict__ homo,
    unsigned long long* __restrict__ lists, unsigned int* __restrict__ cbase,
    unsigned long long* __restrict__ accum) {
  int bx = blockIdx.x, by = blockIdx.y;
  int src = blockIdx.z >> 3, b = blockIdx.z & 7;
  int tid = threadIdx.x;

  __shared__ float in[INH][INW];       // 10.1 KB
  __shared__ float hmax[INH][TW];      // 9.0 KB
  __shared__ unsigned int s_cnt, s_base;
  __shared__ unsigned int s_bh[NBUCKET];
  __shared__ float s_wsum[4];
  __shared__ unsigned int s_wcnt[4];

  if (tid == 0) { s_cnt = 0; s_base = 0; }
  if (tid < NBUCKET) s_bh[tid] = 0;

  const float* hm = homo + b * 9;
  float h0 = hm[0], h1 = hm[1], h2 = hm[2];
  float h3 = hm[3], h4 = hm[4], h5 = hm[5];
  float h6 = hm[6], h7 = hm[7], h8 = hm[8];

  int y0t = by * TH, x0t = bx * TW;

  // Phase 1: stage tile into LDS (compile-time trip counts -> unrolled, deep MLP)
  if (src == 0) {
    #pragma unroll
    for (int it = 0; it < 3; ++it) {
      int i = it * 256 + tid;
      if (i < INH * 18) {
        int r = i / 18, c4 = i % 18;
        int gy = y0t + r - 2;
        int gx0 = x0t - 4 + c4 * 4;
        float4 v = make_float4(0.f, 0.f, 0.f, 0.f);
        if (gy >= PAD && gy < NH - PAD) {
          const float4* p = (const float4*)(score1 + (size_t)b * NHW + (size_t)gy * NW + gx0);
          float4 raw = *p;
          v.x = (gx0 + 0 >= PAD && gx0 + 0 < NW - PAD) ? raw.x : 0.f;
          v.y = (gx0 + 1 >= PAD && gx0 + 1 < NW - PAD) ? raw.y : 0.f;
          v.z = (gx0 + 2 >= PAD && gx0 + 2 < NW - PAD) ? raw.z : 0.f;
          v.w = (gx0 + 3 >= PAD && gx0 + 3 < NW - PAD) ? raw.w : 0.f;
        }
        *(float4*)&in[r][c4 * 4] = v;
      }
    }
  } else {
    const float* img = score2 + b * NHW;
    #pragma unroll
    for (int it = 0; it < 10; ++it) {
      int i = it * 256 + tid;
      if (i < INH * 68) {
        int r = i / 68, c = i % 68;
        int gy = y0t + r - 2, gx = x0t - 2 + c;
        float v = 0.f;
        if (gy >= PAD && gy < NH - PAD && gx >= PAD && gx < NW - PAD) {
          float xf = (float)gx, yf = (float)gy;
          float X = h0 * xf + h1 * yf + h2;
          float Y = h3 * xf + h4 * yf + h5;
          float Z = h6 * xf + h7 * yf + h8;
          float rz = __builtin_amdgcn_rcpf(Z);
          float x2 = X * rz, y2 = Y * rz;
          float x0f = floorf(x2), y0f = floorf(y2);
          float x1f = x0f + 1.f, y1f = y0f + 1.f;
          float wa = (x1f - x2) * (y1f - y2);
          float wb = (x2 - x0f) * (y1f - y2);
          float wc = (x1f - x2) * (y2 - y0f);
          float wd = (x2 - x0f) * (y2 - y0f);
          float acc = 0.f;
          if (x0f >= 0.f && x1f <= 639.f && y0f >= 0.f && y1f <= 511.f) {
            const float* p = img + (int)y0f * NW + (int)x0f;
            acc = fmaf(wa, p[0], acc);
            acc = fmaf(wb, p[1], acc);
            acc = fmaf(wc, p[NW], acc);
            acc = fmaf(wd, p[NW + 1], acc);
          } else {
            corner(img, x0f, y0f, wa, acc);
            corner(img, x1f, y0f, wb, acc);
            corner(img, x0f, y1f, wc, acc);
            corner(img, x1f, y1f, wd, acc);
          }
          v = acc;
        }
        in[r][c + 2] = v;
      }
    }
  }
  __syncthreads();

  // Phase 2: horizontal 5-max. hmax[r][c] = max(in[r][c+2 .. c+6])
  #pragma unroll
  for (int it = 0; it < 9; ++it) {
    int i = it * 256 + tid;
    int r = i >> 6, c = i & 63;
    float m = fmaxf(fmaxf(fmaxf(in[r][c + 2], in[r][c + 3]), fmaxf(in[r][c + 4], in[r][c + 5])),
                    in[r][c + 6]);
    hmax[r][c] = m;
  }
  __syncthreads();

  // src0: block-uniform visibility shortcut (5 linear factors, 4 tile corners)
  bool uni = false;
  float vconst = 0.f;
  if (src == 0) {
    float c00[5], c10[5], c01[5], c11[5];
    vis_parts(h0, h1, h2, h3, h4, h5, h6, h7, h8, (float)x0t, (float)y0t, c00);
    vis_parts(h0, h1, h2, h3, h4, h5, h6, h7, h8, (float)(x0t + TW - 1), (float)y0t, c10);
    vis_parts(h0, h1, h2, h3, h4, h5, h6, h7, h8, (float)x0t, (float)(y0t + TH - 1), c01);
    vis_parts(h0, h1, h2, h3, h4, h5, h6, h7, h8, (float)(x0t + TW - 1), (float)(y0t + TH - 1), c11);
    uni = true;
    bool sig[5];
    #pragma unroll
    for (int q = 0; q < 5; ++q) {
      bool allp = (c00[q] > 0.f) & (c10[q] > 0.f) & (c01[q] > 0.f) & (c11[q] > 0.f);
      bool alln = (c00[q] < 0.f) & (c10[q] < 0.f) & (c01[q] < 0.f) & (c11[q] < 0.f);
      uni = uni & (allp | alln);
      sig[q] = allp;
    }
    vconst = (sig[0] == sig[4] && sig[1] == sig[4] && sig[2] == sig[4] && sig[3] == sig[4])
             ? 1.f : 0.f;
  }

  // Phase 3: vertical 5-max + survivor detection; src0 also dense loss terms
  int nsv = 0;
  float sv[8];
  unsigned int si[8];
  float tsum = 0.f;
  int vcnt = 0;
  #pragma unroll
  for (int it = 0; it < (TH * TW) / 256; ++it) {
    int i = it * 256 + tid;
    int r = i >> 6, c = i & 63;
    int gy = y0t + r, gx = x0t + c;
    float val = in[r + 2][c + 4];
    if (src == 0) {
      float v = uni ? vconst
                    : vis_quad(h0, h1, h2, h3, h4, h5, h6, h7, h8, (float)gx, (float)gy);
      tsum += val * val * v;
      vcnt += (v > 0.f) ? 1 : 0;
    }
    if (val > 0.f) {   // NMS_THRESH = 0
      float m = fmaxf(fmaxf(fmaxf(hmax[r][c], hmax[r + 1][c]), fmaxf(hmax[r + 2][c], hmax[r + 3][c])),
                      hmax[r + 4][c]);
      if (m == val) {
        sv[nsv] = val;
        si[nsv] = (unsigned int)(gy * NW + gx);
        ++nsv;
      }
    }
  }

  // Phase 4: LDS bookkeeping (counter + bucket hist) + wave reduce, 2 barriers
  unsigned int local = 0;
  if (nsv > 0) local = atomicAdd(&s_cnt, (unsigned int)nsv);
  #pragma unroll
  for (int j = 0; j < 8; ++j)
    if (j < nsv) atomicAdd(&s_bh[vbucket(sv[j])], 1u);

  if (src == 0) {
    for (int m = 1; m < 64; m <<= 1) {
      tsum += __shfl_xor(tsum, m, 64);
      vcnt += __shfl_xor(vcnt, m, 64);
    }
    if ((tid & 63) == 0) { s_wsum[tid >> 6] = tsum; s_wcnt[tid >> 6] = (unsigned int)vcnt; }
  }
  __syncthreads();

  int li = src * NB + b;
  if (tid == 0) {
    if (s_cnt > 0) s_base = atomicAdd(&cbase[li * CNT_STRIDE], s_cnt);
    if (src == 0) {
      float ts = s_wsum[0] + s_wsum[1] + s_wsum[2] + s_wsum[3];
      unsigned int vc = s_wcnt[0] + s_wcnt[1] + s_wcnt[2] + s_wcnt[3];
      long long fp = (long long)((double)ts * 4294967296.0);
      atomicAdd(&accum[0], (unsigned long long)fp);
      atomicAdd(&accum[1], (unsigned long long)vc);
    }
  }
  if (tid < NBUCKET && s_bh[tid] > 0)
    atomicAdd(&cbase[BUCKET_BASE + li * NBUCKET + tid], s_bh[tid]);
  __syncthreads();

  unsigned int base = s_base;
  #pragma unroll
  for (int j = 0; j < 8; ++j) {
    if (j < nsv) {
      unsigned int pos = base + local + (unsigned int)j;
      if (pos < CAP) {
        unsigned long long key = ((unsigned long long)__float_as_uint(sv[j]) << 32)
                               | (unsigned long long)(~si[j]);
        lists[(size_t)li * CAP + pos] = key;
      }
    }
  }
}

// Exact top-512 per (source,image): bucket counts -> one gather scan -> RANK select
// (each candidate's rank = count of greater keys; keys unique; LDS broadcast reads).
// src0 -> kp1 out. src1 -> winners rank-sorted by pixel idx asc, written compact.
#define NT 1024
__global__ __launch_bounds__(NT) void k_topk6(
    const unsigned long long* __restrict__ lists, const unsigned int* __restrict__ cbase,
    float* __restrict__ out, unsigned long long* __restrict__ winners,
    unsigned int* __restrict__ wcnt) {
  int li = blockIdx.x;             // 0..15
  int src = li >> 3, b = li & 7;
  int tid = threadIdx.x;

  __shared__ unsigned long long sbuf[GCAP];   // 32 KB candidates
  __shared__ unsigned long long srt[TOPK];    // top-512 sorted desc by (val, idx-asc)
  __shared__ unsigned int s_bc[NBUCKET];
  __shared__ int s_bb;
  __shared__ unsigned int s_nsel;

  unsigned int N = cbase[li * CNT_STRIDE]; if (N > CAP) N = CAP;
  if (tid < NBUCKET) s_bc[tid] = cbase[BUCKET_BASE + li * NBUCKET + tid];
  if (tid == 0) s_nsel = 0;
  __syncthreads();

  if (tid == 0) {
    unsigned int want = (N < TOPK) ? N : TOPK;
    int bb = NBUCKET;
    if (want > 0) {
      unsigned int cum = 0;
      for (int bk = NBUCKET - 1; bk >= 1; --bk) {
        cum += s_bc[bk];
        bb = bk;
        if (cum >= want) break;
      }
    }
    s_bb = bb;
  }
  __syncthreads();
  int bb = s_bb;

  // single gather scan with wave-aggregated LDS push
  const unsigned long long* list = lists + (size_t)li * CAP;
  int lane = tid & 63;
  for (unsigned int i = tid; i < N; i += NT) {
    unsigned long long k = list[i];
    float v = __uint_as_float((unsigned int)(k >> 32));
    bool pred = (vbucket(v) >= bb);
    unsigned long long mask = __ballot(pred);
    if (mask) {
      int leader = __ffsll((long long)mask) - 1;
      unsigned int cnt = (unsigned int)__popcll(mask);
      unsigned int bp = 0;
      if (lane == leader) bp = atomicAdd(&s_nsel, cnt);
      bp = __shfl(bp, leader, 64);
      if (pred) {
        unsigned int pos = bp + (unsigned int)__popcll(mask & ((1ULL << lane) - 1ULL));
        if (pos < GCAP) sbuf[pos] = k;
      }
    }
  }
  __syncthreads();
  unsigned int total = s_nsel; if (total > GCAP) total = GCAP;

  // rank selection: top-512 by full 64-bit key (val desc, idx asc), exact
  for (unsigned int i = tid; i < total; i += NT) {
    unsigned long long key = sbuf[i];
    unsigned int rank = 0;
    for (unsigned int j = 0; j < total; ++j)
      rank += (sbuf[j] > key) ? 1u : 0u;
    if (rank < TOPK) srt[rank] = key;
  }
  for (unsigned int i = total + tid; i < TOPK; i += NT) srt[i] = 0ULL;
  __syncthreads();

  if (src == 0) {
    for (int r = tid; r < TOPK; r += NT) {
      unsigned long long k = srt[r];
      unsigned int idx = (k == 0ULL) ? 0u : ~(unsigned int)(k & 0xFFFFFFFFULL);
      int yy = (int)(idx / NW), xx = (int)(idx % NW);
      out[1 + ((b * TOPK) + r) * 2 + 0] = (float)yy;
      out[1 + ((b * TOPK) + r) * 2 + 1] = (float)xx;
    }
  } else {
    unsigned int nw = (total < TOPK) ? total : TOPK;
    // rank by pixel idx asc among winners; write (idx<<32)|valbits compact
    for (unsigned int i = tid; i < nw; i += NT) {
      unsigned long long k = srt[i];
      unsigned int idx = ~(unsigned int)(k & 0xFFFFFFFFULL);
      unsigned int rank = 0;
      for (unsigned int j = 0; j < nw; ++j) {
        unsigned int idxj = ~(unsigned int)(srt[j] & 0xFFFFFFFFULL);
        rank += (idxj < idx) ? 1u : 0u;
      }
      winners[b * TOPK + rank] = ((unsigned long long)idx << 32) | (k >> 32);
    }
    for (unsigned int i = nw + tid; i < TOPK; i += NT) winners[b * TOPK + i] = ~0ULL;
    if (tid == 0) wcnt[b] = nw;
  }
}

// Sparse gt + correction, gather-based (no gtbuf):
// task = (winner i, tap k). Pixel p = pos_i + offset(k). Contributors found by
// binary search over winners sorted by idx; min-idx contributor owns p.
// Fully deterministic (fixed scan order; integer accumulation only).
__global__ __launch_bounds__(256) void k_gt(
    const float* __restrict__ score1, const float* __restrict__ homo,
    const unsigned long long* __restrict__ winners, const unsigned int* __restrict__ wcnt,
    unsigned long long* __restrict__ accum, unsigned int* __restrict__ dcnt,
    float* __restrict__ out) {
  int b = blockIdx.y;
  int tid = threadIdx.x;
  __shared__ unsigned long long w[TOPK];
  __shared__ float s_red[4];

  unsigned int nw = wcnt[b];
  for (int i = tid; i < TOPK; i += 256)
    w[i] = (i < (int)nw) ? winners[b * TOPK + i] : ~0ULL;
  __syncthreads();

  const float* hm = homo + b * 9;
  float h0 = hm[0], h1 = hm[1], h2 = hm[2];
  float h3 = hm[3], h4 = hm[4], h5 = hm[5];
  float h6 = hm[6], h7 = hm[7], h8 = hm[8];

  const float gw5[5] = {G2, G1, G0, G1, G2};
  unsigned int r = blockIdx.x * 256u + (unsigned int)tid;  // task id in image
  unsigned int i = r / 25u, k = r % 25u;
  float term = 0.f;
  if (i < nw) {
    unsigned long long wk = w[i];
    unsigned int idx = (unsigned int)(wk >> 32);
    int y = (int)(idx / NW), x = (int)(idx % NW);
    int py = y + (int)(k / 5u) - 2, px = x + (int)(k % 5u) - 2;

    float gt = 0.f;
    unsigned int firstIdx = 0xFFFFFFFFu;
    #pragma unroll
    for (int dr = -2; dr <= 2; ++dr) {
      int ry = py + dr;
      unsigned int lo = (unsigned int)(ry * NW + px - 2);
      unsigned int hi = (unsigned int)(ry * NW + px + 2);
      unsigned long long lokey = ((unsigned long long)lo << 32);
      int a = 0, e = TOPK;
      while (a < e) { int m = (a + e) >> 1; if (w[m] < lokey) a = m + 1; else e = m; }
      for (int j = a; j < TOPK; ++j) {
        unsigned long long c = w[j];
        unsigned int cidx = (unsigned int)(c >> 32);
        if (cidx > hi) break;
        float cval = __uint_as_float((unsigned int)(c & 0xFFFFFFFFULL));
        int cx = (int)(cidx % NW);
        gt += cval * gw5[dr + 2] * gw5[cx - px + 2];
        if (firstIdx == 0xFFFFFFFFu) firstIdx = cidx;
      }
    }
    if (firstIdx == idx) {   // this winner owns pixel p -> exactly-once
      float s1 = bordered(score1, b, py, px);
      float v = vis_quad(h0, h1, h2, h3, h4, h5, h6, h7, h8, (float)px, (float)py);
      term = (gt - 2.f * s1) * gt * v;
    }
  }

  for (int m = 1; m < 64; m <<= 1) term += __shfl_xor(term, m, 64);
  if ((tid & 63) == 0) s_red[tid >> 6] = term;
  __syncthreads();
  if (tid == 0) {
    float bsum = s_red[0] + s_red[1] + s_red[2] + s_red[3];
    long long fp = (long long)((double)bsum * 4294967296.0);
    atomicAdd(&accum[0], (unsigned long long)fp);
    __threadfence();
    unsigned int old = atomicAdd(dcnt, 1u);
    if (old == gridDim.x * gridDim.y - 1u) {
      unsigned long long ts = atomicAdd(&accum[0], 0ULL);
      unsigned long long nv = atomicAdd(&accum[1], 0ULL);
      double tsd = (double)(long long)ts / 4294967296.0;
      out[0] = (float)(100.0 * tsd / (double)nv);
    }
  }
}

extern "C" void kernel_launch(void* const* d_in, const int* in_sizes, int n_in,
                              void* d_out, int out_size, void* d_ws, size_t ws_size,
                              hipStream_t stream) {
  const float* score1 = (const float*)d_in[0];
  const float* score2 = (const float*)d_in[1];
  const float* homo   = (const float*)d_in[2];
  float* out = (float*)d_out;

  // workspace layout
  unsigned long long* lists = (unsigned long long*)d_ws;            // 16*CAP u64
  unsigned int* cbase = (unsigned int*)(lists + (size_t)16 * CAP);
  // cbase u32 indices: [0,1024) padded totals; [1024,1536) bucket counts;
  // [1536,1540) accum (2 u64); [1540] dcnt; [1544,1552) wcnt[8]; [1552..) winners
  unsigned long long* accum = (unsigned long long*)(cbase + 1536);
  unsigned int* dcnt = cbase + 1540;
  unsigned int* wcnt = cbase + 1544;
  unsigned long long* winners = (unsigned long long*)(cbase + 1552); // 8*512 u64
  const size_t cbytes = 1544 * 4;   // memset: totals + buckets + accum + dcnt

  size_t required = (size_t)16 * CAP * 8 + 1552 * 4 + (size_t)NB * TOPK * 8;
  if (ws_size < required) return;

  hipMemsetAsync(cbase, 0, cbytes, stream);

  dim3 gnms(NW / TW, NH / TH, 16);    // 10 x 16 x 16 = 2560 blocks
  k_nms4<<<gnms, 256, 0, stream>>>(score1, score2, homo, lists, cbase, accum);
  k_topk6<<<16, NT, 0, stream>>>(lists, cbase, out, winners, wcnt);
  dim3 ggt((TOPK * 25) / 256, NB);    // 50 x 8 = 400 blocks
  k_gt<<<ggt, 256, 0, stream>>>(score1, homo, winners, wcnt, accum, dcnt, out);
}

// Round 15
// 95.258 us; speedup vs baseline: 3.0692x; 1.1486x over previous
//
#include <hip/hip_runtime.h>

#define NB 8
#define NH 512
#define NW 640
#define NHW (NH*NW)
#define TOPK 512
#define PAD 8
#define NBUCKET 32
#define GCAP 4096        // topk gather capacity (32 KB LDS)
#define NTILE 160        // tiles per (source,image): 10 x 16
#define TSLOT 256        // list slots owned per tile (>= 242 max survivors)

// NMS tile geometry (block = 256 threads)
#define TW 64
#define TH 32
#define INH 36          // staged rows:  gy in [by*32-2, by*32+34)
#define INW 72          // staged cols, in[r][k] holds gx = x0t + k - 4

// Gaussian taps exp(-2 d^2); |d|>=3 taps are <=1.52e-8 -> negligible, radius 2 used
#define G0 1.0f
#define G1 0.1353352832366127f
#define G2 3.3546262790251185e-4f

// meta layout (u32 indices)
#define M_TCNT 0          // [0,2560): li*NTILE + t
#define M_THIST 2560      // [2560,84480): (li*NTILE+t)*32 + k
#define M_DENSE 84480     // [84480,87040): (b*NTILE+t)*2 {f32 bits tsum, u32 vcnt}
#define M_WCNT 87040      // 8
#define M_ACCUM 87048     // 4 u64 (8 u32): [0]=corr fp, [2]=dense f64 bits, [3]=nvis
#define M_DCNT 87056
#define M_WINNERS 87064   // 8*512 u64

__device__ __forceinline__ float bordered(const float* __restrict__ img, int b, int y, int x) {
  if (y < PAD || y >= NH - PAD || x < PAD || x >= NW - PAD) return 0.f;
  return img[b * NHW + y * NW + x];
}

// Monotone (weakly increasing in val) bucket index, fine-grained near 1.0.
__device__ __forceinline__ int vbucket(float val) {
  int d = 0x3F800000 - (int)__float_as_uint(val);
  if (d <= 0) return NBUCKET - 1;
  int c = __clz(d);
  return c > 30 ? 30 : c;
}

__device__ __forceinline__ void corner(const float* __restrict__ img, float cx, float cy,
                                       float wgt, float& acc) {
  float valid = (cx >= 0.f && cx <= (float)(NW - 1) && cy >= 0.f && cy <= (float)(NH - 1)) ? 1.f : 0.f;
  float xc = fminf(fmaxf(cx, 0.f), (float)(NW - 1));
  float yc = fminf(fmaxf(cy, 0.f), (float)(NH - 1));
  int xi = (int)xc, yi = (int)yc;
  acc += wgt * img[yi * NW + xi] * valid;
}

// Division-free visibility: v=1 iff x2 in (-1,NW) and y2 in (-1,NH), x2=X/Z.
__device__ __forceinline__ float vis_quad(float h0, float h1, float h2, float h3, float h4,
                                          float h5, float h6, float h7, float h8,
                                          float xf, float yf) {
  float X = h0 * xf + h1 * yf + h2;
  float Y = h3 * xf + h4 * yf + h5;
  float Z = h6 * xf + h7 * yf + h8;
  bool ok = ((X + Z) * Z > 0.f) & ((640.f * Z - X) * Z > 0.f)
          & ((Y + Z) * Z > 0.f) & ((512.f * Z - Y) * Z > 0.f);
  return ok ? 1.f : 0.f;
}

__device__ __forceinline__ void vis_parts(float h0, float h1, float h2, float h3, float h4,
                                          float h5, float h6, float h7, float h8,
                                          float xf, float yf, float L[5]) {
  float X = h0 * xf + h1 * yf + h2;
  float Y = h3 * xf + h4 * yf + h5;
  float Z = h6 * xf + h7 * yf + h8;
  L[0] = X + Z; L[1] = 640.f * Z - X; L[2] = Y + Z; L[3] = 512.f * Z - Y; L[4] = Z;
}

// Fused: one block processes BOTH sources for its tile (all blocks co-resident).
// Tile-owned output slots -> zero global atomics, no pre-zeroed state needed.
__global__ __launch_bounds__(256) void k_nms5(
    const float* __restrict__ score1, const float* __restrict__ score2,
    const float* __restrict__ homo,
    unsigned long long* __restrict__ lists, unsigned int* __restrict__ meta) {
  int bx = blockIdx.x, by = blockIdx.y, b = blockIdx.z;
  int tid = threadIdx.x;
  int t = by * 10 + bx;                 // tile id 0..159

  __shared__ float in[INH][INW];        // 10.1 KB
  __shared__ float hmax[INH][TW];       // 9.0 KB
  __shared__ unsigned int s_cnt;
  __shared__ unsigned int s_bh[NBUCKET];
  __shared__ float s_wsum[4];
  __shared__ unsigned int s_wcnt[4];

  const float* hm = homo + b * 9;
  float h0 = hm[0], h1 = hm[1], h2 = hm[2];
  float h3 = hm[3], h4 = hm[4], h5 = hm[5];
  float h6 = hm[6], h7 = hm[7], h8 = hm[8];

  int y0t = by * TH, x0t = bx * TW;

  for (int src = 0; src < 2; ++src) {
    // init per-pass LDS bookkeeping
    if (tid == 0) s_cnt = 0;
    if (tid < NBUCKET) s_bh[tid] = 0;

    // Phase 1: stage tile into LDS (border-filtered values)
    if (src == 0) {
      #pragma unroll
      for (int it = 0; it < 3; ++it) {
        int i = it * 256 + tid;
        if (i < INH * 18) {
          int r = i / 18, c4 = i % 18;
          int gy = y0t + r - 2;
          int gx0 = x0t - 4 + c4 * 4;
          float4 v = make_float4(0.f, 0.f, 0.f, 0.f);
          if (gy >= PAD && gy < NH - PAD) {
            const float4* p = (const float4*)(score1 + (size_t)b * NHW + (size_t)gy * NW + gx0);
            float4 raw = *p;
            v.x = (gx0 + 0 >= PAD && gx0 + 0 < NW - PAD) ? raw.x : 0.f;
            v.y = (gx0 + 1 >= PAD && gx0 + 1 < NW - PAD) ? raw.y : 0.f;
            v.z = (gx0 + 2 >= PAD && gx0 + 2 < NW - PAD) ? raw.z : 0.f;
            v.w = (gx0 + 3 >= PAD && gx0 + 3 < NW - PAD) ? raw.w : 0.f;
          }
          *(float4*)&in[r][c4 * 4] = v;
        }
      }
    } else {
      const float* img = score2 + b * NHW;
      #pragma unroll
      for (int it = 0; it < 10; ++it) {
        int i = it * 256 + tid;
        if (i < INH * 68) {
          int r = i / 68, c = i % 68;
          int gy = y0t + r - 2, gx = x0t - 2 + c;
          float v = 0.f;
          if (gy >= PAD && gy < NH - PAD && gx >= PAD && gx < NW - PAD) {
            float xf = (float)gx, yf = (float)gy;
            float X = h0 * xf + h1 * yf + h2;
            float Y = h3 * xf + h4 * yf + h5;
            float Z = h6 * xf + h7 * yf + h8;
            float rz = __builtin_amdgcn_rcpf(Z);
            float x2 = X * rz, y2 = Y * rz;
            float x0f = floorf(x2), y0f = floorf(y2);
            float x1f = x0f + 1.f, y1f = y0f + 1.f;
            float wa = (x1f - x2) * (y1f - y2);
            float wb = (x2 - x0f) * (y1f - y2);
            float wc = (x1f - x2) * (y2 - y0f);
            float wd = (x2 - x0f) * (y2 - y0f);
            float acc = 0.f;
            if (x0f >= 0.f && x1f <= 639.f && y0f >= 0.f && y1f <= 511.f) {
              const float* p = img + (int)y0f * NW + (int)x0f;
              acc = fmaf(wa, p[0], acc);
              acc = fmaf(wb, p[1], acc);
              acc = fmaf(wc, p[NW], acc);
              acc = fmaf(wd, p[NW + 1], acc);
            } else {
              corner(img, x0f, y0f, wa, acc);
              corner(img, x1f, y0f, wb, acc);
              corner(img, x0f, y1f, wc, acc);
              corner(img, x1f, y1f, wd, acc);
            }
            v = acc;
          }
          in[r][c + 2] = v;
        }
      }
    }
    __syncthreads();

    // Phase 2: horizontal 5-max
    #pragma unroll
    for (int it = 0; it < 9; ++it) {
      int i = it * 256 + tid;
      int r = i >> 6, c = i & 63;
      float m = fmaxf(fmaxf(fmaxf(in[r][c + 2], in[r][c + 3]), fmaxf(in[r][c + 4], in[r][c + 5])),
                      in[r][c + 6]);
      hmax[r][c] = m;
    }
    __syncthreads();

    // src0: block-uniform visibility shortcut
    bool uni = false;
    float vconst = 0.f;
    if (src == 0) {
      float c00[5], c10[5], c01[5], c11[5];
      vis_parts(h0, h1, h2, h3, h4, h5, h6, h7, h8, (float)x0t, (float)y0t, c00);
      vis_parts(h0, h1, h2, h3, h4, h5, h6, h7, h8, (float)(x0t + TW - 1), (float)y0t, c10);
      vis_parts(h0, h1, h2, h3, h4, h5, h6, h7, h8, (float)x0t, (float)(y0t + TH - 1), c01);
      vis_parts(h0, h1, h2, h3, h4, h5, h6, h7, h8, (float)(x0t + TW - 1), (float)(y0t + TH - 1), c11);
      uni = true;
      bool sig[5];
      #pragma unroll
      for (int q = 0; q < 5; ++q) {
        bool allp = (c00[q] > 0.f) & (c10[q] > 0.f) & (c01[q] > 0.f) & (c11[q] > 0.f);
        bool alln = (c00[q] < 0.f) & (c10[q] < 0.f) & (c01[q] < 0.f) & (c11[q] < 0.f);
        uni = uni & (allp | alln);
        sig[q] = allp;
      }
      vconst = (sig[0] == sig[4] && sig[1] == sig[4] && sig[2] == sig[4] && sig[3] == sig[4])
               ? 1.f : 0.f;
    }

    // Phase 3: vertical 5-max + survivor detection (+dense loss terms, src0)
    int nsv = 0;
    float sv[8];
    unsigned int si[8];
    float tsum = 0.f;
    int vcnt = 0;
    #pragma unroll
    for (int it = 0; it < (TH * TW) / 256; ++it) {
      int i = it * 256 + tid;
      int r = i >> 6, c = i & 63;
      int gy = y0t + r, gx = x0t + c;
      float val = in[r + 2][c + 4];
      if (src == 0) {
        float v = uni ? vconst
                      : vis_quad(h0, h1, h2, h3, h4, h5, h6, h7, h8, (float)gx, (float)gy);
        tsum += val * val * v;
        vcnt += (v > 0.f) ? 1 : 0;
      }
      if (val > 0.f) {   // NMS_THRESH = 0
        float m = fmaxf(fmaxf(fmaxf(hmax[r][c], hmax[r + 1][c]), fmaxf(hmax[r + 2][c], hmax[r + 3][c])),
                        hmax[r + 4][c]);
        if (m == val) {
          sv[nsv] = val;
          si[nsv] = (unsigned int)(gy * NW + gx);
          ++nsv;
        }
      }
    }

    // Phase 4: LDS bookkeeping + wave reduce, 1 barrier, then plain-store readout
    unsigned int local = 0;
    if (nsv > 0) local = atomicAdd(&s_cnt, (unsigned int)nsv);
    #pragma unroll
    for (int j = 0; j < 8; ++j)
      if (j < nsv) atomicAdd(&s_bh[vbucket(sv[j])], 1u);

    if (src == 0) {
      for (int m = 1; m < 64; m <<= 1) {
        tsum += __shfl_xor(tsum, m, 64);
        vcnt += __shfl_xor(vcnt, m, 64);
      }
      if ((tid & 63) == 0) { s_wsum[tid >> 6] = tsum; s_wcnt[tid >> 6] = (unsigned int)vcnt; }
    }
    __syncthreads();

    int li = src * NB + b;
    if (tid == 0)
      meta[M_TCNT + li * NTILE + t] = (s_cnt < (unsigned)TSLOT) ? s_cnt : (unsigned)TSLOT;
    if (tid < NBUCKET)
      meta[M_THIST + (li * NTILE + t) * 32 + tid] = s_bh[tid];
    if (src == 0 && tid == 0) {
      float ts = s_wsum[0] + s_wsum[1] + s_wsum[2] + s_wsum[3];
      unsigned int vc = s_wcnt[0] + s_wcnt[1] + s_wcnt[2] + s_wcnt[3];
      meta[M_DENSE + (b * NTILE + t) * 2 + 0] = __float_as_uint(ts);
      meta[M_DENSE + (b * NTILE + t) * 2 + 1] = vc;
    }
    #pragma unroll
    for (int j = 0; j < 8; ++j) {
      if (j < nsv && local + (unsigned)j < (unsigned)TSLOT) {
        unsigned long long key = ((unsigned long long)__float_as_uint(sv[j]) << 32)
                               | (unsigned long long)(~si[j]);
        lists[(size_t)li * (NTILE * TSLOT) + t * TSLOT + local + j] = key;
      }
    }
    __syncthreads();   // before LDS reuse / re-init in next pass
  }
}

// Exact top-512 per (source,image) from tile-sliced lists:
// aggregate per-tile hists -> boundary bucket -> predicated gather -> rank select.
// src0 -> kp1 out. src1 -> winners rank-sorted by pixel idx asc, written compact.
// Block li==0 also zeroes accum[0]/dcnt for k_gt2 (stream-ordered).
#define NT 1024
__global__ __launch_bounds__(NT) void k_topk8(
    const unsigned long long* __restrict__ lists, unsigned int* __restrict__ meta,
    float* __restrict__ out) {
  int li = blockIdx.x;             // 0..15
  int src = li >> 3, b = li & 7;
  int tid = threadIdx.x;

  __shared__ unsigned long long sbuf[GCAP];   // 32 KB candidates
  __shared__ unsigned long long srt[TOPK];
  __shared__ unsigned int scnt[NTILE];
  __shared__ unsigned int s_bc[NBUCKET];
  __shared__ int s_bb;
  __shared__ unsigned int s_nsel;

  if (tid < NTILE) scnt[tid] = meta[M_TCNT + li * NTILE + tid];
  if (tid < NBUCKET) s_bc[tid] = 0;
  if (tid == 0) s_nsel = 0;
  if (li == 0 && tid == 0) {
    ((unsigned long long*)(meta + M_ACCUM))[0] = 0ULL;   // correction accum
    meta[M_DCNT] = 0u;
  }
  __syncthreads();

  for (int i = tid; i < NTILE * 32; i += NT)
    atomicAdd(&s_bc[i & 31], meta[M_THIST + li * (NTILE * 32) + i]);
  __syncthreads();

  if (tid == 0) {
    unsigned int N = 0;
    for (int k = 0; k < NBUCKET; ++k) N += s_bc[k];
    unsigned int want = (N < TOPK) ? N : TOPK;
    int bb = NBUCKET;
    if (want > 0) {
      unsigned int cum = 0;
      for (int bk = NBUCKET - 1; bk >= 1; --bk) {
        cum += s_bc[bk];
        bb = bk;
        if (cum >= want) break;
      }
    }
    s_bb = bb;
  }
  __syncthreads();
  int bb = s_bb;

  // predicated gather over tile-sliced slots, wave-aggregated LDS push
  const unsigned long long* list = lists + (size_t)li * (NTILE * TSLOT);
  int lane = tid & 63;
  for (unsigned int s = tid; s < NTILE * TSLOT; s += NT) {
    unsigned int t = s >> 8, j = s & 255u;
    bool pred = (j < scnt[t]);
    unsigned long long k = 0ULL;
    if (pred) {
      k = list[s];
      float v = __uint_as_float((unsigned int)(k >> 32));
      pred = (vbucket(v) >= bb);
    }
    unsigned long long mask = __ballot(pred);
    if (mask) {
      int leader = __ffsll((long long)mask) - 1;
      unsigned int cnt = (unsigned int)__popcll(mask);
      unsigned int bp = 0;
      if (lane == leader) bp = atomicAdd(&s_nsel, cnt);
      bp = __shfl(bp, leader, 64);
      if (pred) {
        unsigned int pos = bp + (unsigned int)__popcll(mask & ((1ULL << lane) - 1ULL));
        if (pos < GCAP) sbuf[pos] = k;
      }
    }
  }
  __syncthreads();
  unsigned int total = s_nsel; if (total > GCAP) total = GCAP;

  // rank selection: top-512 by full 64-bit key (val desc, idx asc), exact
  for (unsigned int i = tid; i < total; i += NT) {
    unsigned long long key = sbuf[i];
    unsigned int rank = 0;
    for (unsigned int j = 0; j < total; ++j)
      rank += (sbuf[j] > key) ? 1u : 0u;
    if (rank < TOPK) srt[rank] = key;
  }
  for (unsigned int i = total + tid; i < TOPK; i += NT) srt[i] = 0ULL;
  __syncthreads();

  if (src == 0) {
    for (int r = tid; r < TOPK; r += NT) {
      unsigned long long k = srt[r];
      unsigned int idx = (k == 0ULL) ? 0u : ~(unsigned int)(k & 0xFFFFFFFFULL);
      int yy = (int)(idx / NW), xx = (int)(idx % NW);
      out[1 + ((b * TOPK) + r) * 2 + 0] = (float)yy;
      out[1 + ((b * TOPK) + r) * 2 + 1] = (float)xx;
    }
  } else {
    unsigned int nw = (total < TOPK) ? total : TOPK;
    unsigned long long* winners = (unsigned long long*)(meta + M_WINNERS);
    for (unsigned int i = tid; i < nw; i += NT) {
      unsigned long long k = srt[i];
      unsigned int idx = ~(unsigned int)(k & 0xFFFFFFFFULL);
      unsigned int rank = 0;
      for (unsigned int j = 0; j < nw; ++j) {
        unsigned int idxj = ~(unsigned int)(srt[j] & 0xFFFFFFFFULL);
        rank += (idxj < idx) ? 1u : 0u;
      }
      winners[b * TOPK + rank] = ((unsigned long long)idx << 32) | (k >> 32);
    }
    for (unsigned int i = nw + tid; i < TOPK; i += NT) winners[b * TOPK + i] = ~0ULL;
    if (tid == 0) meta[M_WCNT + b] = nw;
  }
}

// Sparse gt + correction (gather, owner rule) + final loss.
// Block (0,0) additionally reduces the dense partials (fixed order, f64).
__global__ __launch_bounds__(256) void k_gt2(
    const float* __restrict__ score1, const float* __restrict__ homo,
    unsigned int* __restrict__ meta, float* __restrict__ out) {
  int b = blockIdx.y;
  int tid = threadIdx.x;
  __shared__ unsigned long long w[TOPK];
  __shared__ float s_red[4];
  __shared__ double s_dd[4];
  __shared__ unsigned long long s_dn[4];

  unsigned long long* accum = (unsigned long long*)(meta + M_ACCUM);
  const unsigned long long* winners = (const unsigned long long*)(meta + M_WINNERS);
  unsigned int nw = meta[M_WCNT + b];
  for (int i = tid; i < TOPK; i += 256)
    w[i] = (i < (int)nw) ? winners[b * TOPK + i] : ~0ULL;
  __syncthreads();

  const float* hm = homo + b * 9;
  float h0 = hm[0], h1 = hm[1], h2 = hm[2];
  float h3 = hm[3], h4 = hm[4], h5 = hm[5];
  float h6 = hm[6], h7 = hm[7], h8 = hm[8];

  const float gw5[5] = {G2, G1, G0, G1, G2};
  unsigned int r = blockIdx.x * 256u + (unsigned int)tid;  // task id in image
  unsigned int i = r / 25u, k = r % 25u;
  float term = 0.f;
  if (i < nw) {
    unsigned long long wk = w[i];
    unsigned int idx = (unsigned int)(wk >> 32);
    int y = (int)(idx / NW), x = (int)(idx % NW);
    int py = y + (int)(k / 5u) - 2, px = x + (int)(k % 5u) - 2;

    float gt = 0.f;
    unsigned int firstIdx = 0xFFFFFFFFu;
    #pragma unroll
    for (int dr = -2; dr <= 2; ++dr) {
      int ry = py + dr;
      unsigned int lo = (unsigned int)(ry * NW + px - 2);
      unsigned int hi = (unsigned int)(ry * NW + px + 2);
      unsigned long long lokey = ((unsigned long long)lo << 32);
      int a = 0, e = TOPK;
      while (a < e) { int m = (a + e) >> 1; if (w[m] < lokey) a = m + 1; else e = m; }
      for (int j = a; j < TOPK; ++j) {
        unsigned long long c = w[j];
        unsigned int cidx = (unsigned int)(c >> 32);
        if (cidx > hi) break;
        float cval = __uint_as_float((unsigned int)(c & 0xFFFFFFFFULL));
        int cx = (int)(cidx % NW);
        gt += cval * gw5[dr + 2] * gw5[cx - px + 2];
        if (firstIdx == 0xFFFFFFFFu) firstIdx = cidx;
      }
    }
    if (firstIdx == idx) {   // this winner owns pixel p -> exactly-once
      float s1 = bordered(score1, b, py, px);
      float v = vis_quad(h0, h1, h2, h3, h4, h5, h6, h7, h8, (float)px, (float)py);
      term = (gt - 2.f * s1) * gt * v;
    }
  }

  for (int m = 1; m < 64; m <<= 1) term += __shfl_xor(term, m, 64);
  if ((tid & 63) == 0) s_red[tid >> 6] = term;

  // block (0,0): deterministic dense reduction (fixed order, f64)
  if (blockIdx.x == 0 && blockIdx.y == 0) {
    double dsum = 0.0;
    unsigned long long dn = 0;
    for (int i2 = tid; i2 < NB * NTILE; i2 += 256) {
      dsum += (double)__uint_as_float(meta[M_DENSE + 2 * i2]);
      dn += (unsigned long long)meta[M_DENSE + 2 * i2 + 1];
    }
    for (int m = 1; m < 64; m <<= 1) {
      dsum += __shfl_xor(dsum, m, 64);
      dn += (unsigned long long)__shfl_xor((long long)dn, m, 64) - dn + dn;  // careful
    }
    // redo count reduce safely via LDS (shfl of 64-bit unsigned above is messy)
    if ((tid & 63) == 0) { s_dd[tid >> 6] = dsum; }
    __syncthreads();
    // recompute dn via LDS tree to be safe
    __shared__ unsigned long long s_cnt64[256];
    s_cnt64[tid] = 0;
    unsigned long long dn2 = 0;
    for (int i2 = tid; i2 < NB * NTILE; i2 += 256)
      dn2 += (unsigned long long)meta[M_DENSE + 2 * i2 + 1];
    s_cnt64[tid] = dn2;
    __syncthreads();
    for (int s = 128; s > 0; s >>= 1) {
      if (tid < s) s_cnt64[tid] += s_cnt64[tid + s];
      __syncthreads();
    }
    if (tid == 0) {
      double dtot = s_dd[0] + s_dd[1] + s_dd[2] + s_dd[3];
      accum[2] = (unsigned long long)__double_as_longlong(dtot);
      accum[3] = s_cnt64[0];
    }
  }
  __syncthreads();

  if (tid == 0) {
    float bsum = s_red[0] + s_red[1] + s_red[2] + s_red[3];
    long long fp = (long long)((double)bsum * 4294967296.0);
    atomicAdd(&accum[0], (unsigned long long)fp);
    __threadfence();
    unsigned int old = atomicAdd(meta + M_DCNT, 1u);
    if (old == gridDim.x * gridDim.y - 1u) {
      unsigned long long corr = atomicAdd(&accum[0], 0ULL);
      unsigned long long dbits = atomicAdd(&accum[2], 0ULL);
      unsigned long long nv = atomicAdd(&accum[3], 0ULL);
      double dense = __longlong_as_double((long long)dbits);
      double corrd = (double)(long long)corr / 4294967296.0;
      out[0] = (float)(100.0 * (dense + corrd) / (double)nv);
    }
  }
}

extern "C" void kernel_launch(void* const* d_in, const int* in_sizes, int n_in,
                              void* d_out, int out_size, void* d_ws, size_t ws_size,
                              hipStream_t stream) {
  const float* score1 = (const float*)d_in[0];
  const float* score2 = (const float*)d_in[1];
  const float* homo   = (const float*)d_in[2];
  float* out = (float*)d_out;

  unsigned long long* lists = (unsigned long long*)d_ws;   // 16 * 160*256 u64 = 5.24 MB
  unsigned int* meta = (unsigned int*)(lists + (size_t)16 * NTILE * TSLOT);

  size_t required = (size_t)16 * NTILE * TSLOT * 8 + (size_t)(M_WINNERS + 8192) * 4;
  if (ws_size < required) return;

  dim3 gnms(NW / TW, NH / TH, NB);    // 10 x 16 x 8 = 1280 blocks, all co-resident
  k_nms5<<<gnms, 256, 0, stream>>>(score1, score2, homo, lists, meta);
  k_topk8<<<16, NT, 0, stream>>>(lists, meta, out);
  dim3 ggt((TOPK * 25) / 256, NB);    // 50 x 8 = 400 blocks
  k_gt2<<<ggt, 256, 0, stream>>>(score1, homo, meta, out);
}